// Round 3
// baseline (865.909 us; speedup 1.0000x reference)
//
#include <hip/hip_runtime.h>
#include <math.h>

// Problem constants (fixed by reference):
//   x: [B=32, C=512, H=64, W=64] fp32; HW = 4096
//   fc1_w: [64, 768], fc1_b: [64], fc2_w: [1,64], fc2_b: [1]
// Algebraic collapse (harness-verified rounds 0/2, absmax <= 0.008):
//   xc[b,c]  = mean_{hw} x[b,c,hw]
//   q[b,m]   = mean(xc[b,4m..4m+3])                       (m < 128)
//   s[b,c,h] = relu(T1[b,h] + xc[b,c]*T2[b,h] + fc1_b[h])
//     T1[b,h] = sum_f xc[b,f] * w[h,f]                     (f < 512)
//     T2[b,h] = sum_m q[b,m] * (w[h,512+m] + w[h,640+m])   (m < 128)
//   a[b,c]   = sigmoid(fc2_b + sum_h fc2_w[h]*s[b,c,h])
//   out      = x * a[b,c]
//
// Round 3 structure: SINGLE kernel. Cooperative launch is dead on this harness
// (round-1 failure), so cross-block sync is a per-batch arrive/spin on
// device-scope atomics. Block i waits only for its 31 siblings (same batch).
// Deadlock-free: __launch_bounds__(256,4) + 3KiB LDS + small VGPR => all
// 1024 blocks co-resident (4 blocks/CU x 256 CU).

#define B_  32
#define C_  512
#define HW_ 4096
#define ROWS_ (B_ * C_)        // 16384
#define NBLK_ 1024
#define RPB_  16               // rows per block (one batch per block)
#define BLKS_PER_BATCH_ 32     // 512 / 16

typedef float f32x4 __attribute__((ext_vector_type(4)));

__global__ __launch_bounds__(256, 4) void fused(
        const float* __restrict__ x,
        const float* __restrict__ fc1w,
        const float* __restrict__ fc1b,
        const float* __restrict__ fc2w,
        const float* __restrict__ fc2b,
        float* __restrict__ out,
        float* __restrict__ xc,
        int* __restrict__ cnt) {
    const int tid  = threadIdx.x;
    const int lane = tid & 63;
    const int wave = tid >> 6;
    const int row_lo = blockIdx.x * RPB_;   // 16 rows, all in one batch
    const int b  = row_lo / C_;
    const int c0 = row_lo % C_;

    __shared__ float xcs[C_];
    __shared__ float qs[128];
    __shared__ float p1[256], p2[256];
    __shared__ float s1[64], s2[64], w2s[64];
    __shared__ float as[16];

    // ---------- Phase 1: means of this block's 16 rows ----------
    // wave w owns rows 4w..4w+3; 64 lanes x 16 float4 per row, coalesced.
#pragma unroll
    for (int r = 0; r < 4; ++r) {
        const int row = row_lo + wave * 4 + r;
        const f32x4* xr = (const f32x4*)(x + (size_t)row * HW_);
        float s = 0.f;
#pragma unroll
        for (int j = 0; j < 16; ++j) {
            f32x4 v = xr[lane + j * 64];
            s += (v[0] + v[1]) + (v[2] + v[3]);
        }
#pragma unroll
        for (int off = 32; off > 0; off >>= 1) s += __shfl_down(s, off, 64);
        if (lane == 0) xc[row] = s * (1.0f / (float)HW_);
    }

    // preload fc2 weights while waiting is about to happen
    if (tid < 64) w2s[tid] = fc2w[tid];

    // ---------- arrive + per-batch spin ----------
    __threadfence();          // publish xc writes device-wide (release)
    __syncthreads();
    if (tid == 0) {
        atomicAdd(&cnt[b], 1);
        while (__hip_atomic_load(&cnt[b], __ATOMIC_ACQUIRE,
                                 __HIP_MEMORY_SCOPE_AGENT) < BLKS_PER_BATCH_) {
            __builtin_amdgcn_s_sleep(8);
        }
    }
    __syncthreads();
    __threadfence();          // acquire for all threads' xc loads

    // ---------- Phase 2: attention scalars for this block's 16 channels ----
    xcs[tid]       = xc[b * C_ + tid];
    xcs[tid + 256] = xc[b * C_ + 256 + tid];
    __syncthreads();

    if (tid < 128) {
        qs[tid] = (xcs[4 * tid] + xcs[4 * tid + 1] +
                   xcs[4 * tid + 2] + xcs[4 * tid + 3]) * 0.25f;
    }
    __syncthreads();

    {   // T1[h], T2[h]: 4 partial threads per h (fc1w is L2-resident)
        const int h = tid & 63, part = tid >> 6;
        const float* w = fc1w + h * 768;
        float t1 = 0.f, t2 = 0.f;
        const int f0 = part * 128;
#pragma unroll 8
        for (int f = 0; f < 128; ++f) t1 += xcs[f0 + f] * w[f0 + f];
        const int m0 = part * 32;
#pragma unroll 8
        for (int m = 0; m < 32; ++m)
            t2 += qs[m0 + m] * (w[512 + m0 + m] + w[640 + m0 + m]);
        p1[tid] = t1;
        p2[tid] = t2;
    }
    __syncthreads();
    if (tid < 64) {
        s1[tid] = (p1[tid] + p1[tid + 64]) + (p1[tid + 128] + p1[tid + 192]) + fc1b[tid];
        s2[tid] = (p2[tid] + p2[tid + 64]) + (p2[tid + 128] + p2[tid + 192]);
    }
    __syncthreads();

    if (tid < 16) {
        const float xv = xcs[c0 + tid];
        float acc = fc2b[0];
#pragma unroll 8
        for (int hh = 0; hh < 64; ++hh) {
            float z = s1[hh] + xv * s2[hh];
            acc += w2s[hh] * (z > 0.f ? z : 0.f);
        }
        as[tid] = 1.0f / (1.0f + __expf(-acc));
    }
    __syncthreads();

    // ---------- Phase 3: out = x * a, re-reading this block's OWN rows ----
    // Same 256 KiB this block just read in phase 1 -> L2/L3 temporal locality.
    // NT stores keep the write stream from evicting cached x.
#pragma unroll
    for (int r = 0; r < 4; ++r) {
        const int ri  = wave * 4 + r;             // 0..15
        const int row = row_lo + ri;
        const float sc = as[ri];
        const f32x4* xr = (const f32x4*)(x + (size_t)row * HW_);
        f32x4* outr     = (f32x4*)(out + (size_t)row * HW_);
#pragma unroll
        for (int j = 0; j < 16; ++j) {
            f32x4 v = xr[lane + j * 64];
            v *= sc;
            __builtin_nontemporal_store(v, &outr[lane + j * 64]);
        }
    }
}

extern "C" void kernel_launch(void* const* d_in, const int* in_sizes, int n_in,
                              void* d_out, int out_size, void* d_ws, size_t ws_size,
                              hipStream_t stream) {
    const float* x     = (const float*)d_in[0];
    const float* fc1_w = (const float*)d_in[1];
    const float* fc1_b = (const float*)d_in[2];
    const float* fc2_w = (const float*)d_in[3];
    const float* fc2_b = (const float*)d_in[4];
    float* out = (float*)d_out;

    int*   cnt = (int*)d_ws;             // 32 ints (first 128 B)
    float* xc  = (float*)d_ws + 64;      // 16384 floats, 256-B aligned

    hipMemsetAsync(d_ws, 0, 128, stream);   // zero batch counters (capture-safe)
    fused<<<NBLK_, 256, 0, stream>>>(x, fc1_w, fc1_b, fc2_w, fc2_b, out, xc, cnt);
}